// Round 2
// baseline (2454.034 us; speedup 1.0000x reference)
//
#include <hip/hip_runtime.h>
#include <hip/hip_fp16.h>
#include <math.h>

#define B_ 64
#define N_ 512
#define H_ 32
#define E_ 4
#define NSTEPS 5
#define KTOT 2048   // N_*E_

typedef _Float16 half8 __attribute__((ext_vector_type(8)));
typedef float   f32x4 __attribute__((ext_vector_type(4)));

// ---------------------------------------------------------------- init h <- x
__global__ __launch_bounds__(256) void k_init_h(const float* __restrict__ x,
                                                float* __restrict__ h) {
    int i = blockIdx.x * blockDim.x + threadIdx.x;   // 262144 float4s
    ((f32x4*)h)[i] = ((const f32x4*)x)[i];
}

// ---------------------------------------------------------------- s projection
// s_in[b, k=e*512+n', h] = h_state[b,n'] . W_in[h*4+e,:] + b_in[h*4+e]
// stored transposed, split fp16 (hi + lo residual): sT_*_hi/lo[b][h][k]
__global__ __launch_bounds__(256) void k_s(const float* __restrict__ hstate,
                                           const float* __restrict__ W_in,
                                           const float* __restrict__ b_in,
                                           const float* __restrict__ W_out,
                                           const float* __restrict__ b_out,
                                           _Float16* __restrict__ sT_in_hi,
                                           _Float16* __restrict__ sT_in_lo,
                                           _Float16* __restrict__ sT_out_hi,
                                           _Float16* __restrict__ sT_out_lo) {
    int b  = blockIdx.x >> 3;
    int n0 = (blockIdx.x & 7) * 64;
    int lane = threadIdx.x & 63;
    int w = __builtin_amdgcn_readfirstlane((int)(threadIdx.x >> 6)); // 0..3
    int n = n0 + lane;

    const float* hrow = hstate + ((size_t)b * N_ + n) * H_;
    f32x4 hv[8];
#pragma unroll
    for (int c = 0; c < 8; c++) hv[c] = ((const f32x4*)hrow)[c];

#pragma unroll 4
    for (int o = 0; o < 32; o++) {
        int he = w * 32 + o;                 // wave-uniform -> s_load for W
        const f32x4* wr = (const f32x4*)(W_in + (size_t)he * H_);
        float acc = b_in[he];
#pragma unroll
        for (int c = 0; c < 8; c++) {
            f32x4 wv = wr[c];
            acc += hv[c][0]*wv[0] + hv[c][1]*wv[1] + hv[c][2]*wv[2] + hv[c][3]*wv[3];
        }
        int hh = he >> 2, e = he & 3;
        size_t idx = ((size_t)b * H_ + hh) * KTOT + e * N_ + n;
        _Float16 hi = (_Float16)acc;
        _Float16 lo = (_Float16)(acc - (float)hi);
        sT_in_hi[idx] = hi;
        sT_in_lo[idx] = lo;
    }
#pragma unroll 4
    for (int o = 0; o < 32; o++) {
        int he = w * 32 + o;
        const f32x4* wr = (const f32x4*)(W_out + (size_t)he * H_);
        float acc = b_out[he];
#pragma unroll
        for (int c = 0; c < 8; c++) {
            f32x4 wv = wr[c];
            acc += hv[c][0]*wv[0] + hv[c][1]*wv[1] + hv[c][2]*wv[2] + hv[c][3]*wv[3];
        }
        int hh = he >> 2, e = he & 3;
        size_t idx = ((size_t)b * H_ + hh) * KTOT + e * N_ + n;
        _Float16 hi = (_Float16)acc;
        _Float16 lo = (_Float16)(acc - (float)hi);
        sT_out_hi[idx] = hi;
        sT_out_lo[idx] = lo;
    }
}

// ---------------------------------------------------------------- big einsum
// a[b,n,h] = sum_k m[b,n,(dir?K:0)+k] * sT[b][h][k], dir = blockIdx.z
// Split-fp16 MFMA: A=Ahi+Alo (m), B=Bhi+Blo (sT);
// D += Ahi*Bhi + Ahi*Blo + Alo*Bhi  (fp32 accumulate; Alo*Blo ~2^-24, dropped)
__global__ __launch_bounds__(256) void k_einsum(const float* __restrict__ m,
                                                const _Float16* __restrict__ sT_in_hi,
                                                const _Float16* __restrict__ sT_in_lo,
                                                const _Float16* __restrict__ sT_out_hi,
                                                const _Float16* __restrict__ sT_out_lo,
                                                float* __restrict__ a_in,
                                                float* __restrict__ a_out) {
    int dir = blockIdx.z;
    int b   = blockIdx.y;
    int n0  = blockIdx.x * 64;
    int tid  = threadIdx.x;
    int w    = tid >> 6;
    int lane = tid & 63;
    int l15  = lane & 15;
    int quad = lane >> 4;

    const _Float16* sHi = (dir ? sT_out_hi : sT_in_hi) + (size_t)b * H_ * KTOT;
    const _Float16* sLo = (dir ? sT_out_lo : sT_in_lo) + (size_t)b * H_ * KTOT;
    float* aout = dir ? a_out : a_in;

    int row = n0 + w * 16 + l15;     // A-frag row (m row)
    const float* mrow = m + ((size_t)b * N_ + row) * (2 * KTOT) + (size_t)dir * KTOT;

    f32x4 acc0 = {0.f,0.f,0.f,0.f}, acc1 = {0.f,0.f,0.f,0.f};

#pragma unroll 2
    for (int ks = 0; ks < KTOT; ks += 32) {
        int ko = ks + quad * 8;
        f32x4 a0 = *(const f32x4*)(mrow + ko);
        f32x4 a1 = *(const f32x4*)(mrow + ko + 4);
        half8 Bhi0 = *(const half8*)(sHi + (size_t)l15        * KTOT + ko);
        half8 Bhi1 = *(const half8*)(sHi + (size_t)(l15 + 16) * KTOT + ko);
        half8 Blo0 = *(const half8*)(sLo + (size_t)l15        * KTOT + ko);
        half8 Blo1 = *(const half8*)(sLo + (size_t)(l15 + 16) * KTOT + ko);

        half8 Ahi, Alo;
#pragma unroll
        for (int j = 0; j < 4; j++) {
            float v0 = a0[j], v1 = a1[j];
            _Float16 h0 = (_Float16)v0, h1 = (_Float16)v1;
            Ahi[j]     = h0;
            Ahi[j + 4] = h1;
            Alo[j]     = (_Float16)(v0 - (float)h0);
            Alo[j + 4] = (_Float16)(v1 - (float)h1);
        }
        acc0 = __builtin_amdgcn_mfma_f32_16x16x32_f16(Ahi, Bhi0, acc0, 0, 0, 0);
        acc1 = __builtin_amdgcn_mfma_f32_16x16x32_f16(Ahi, Bhi1, acc1, 0, 0, 0);
        acc0 = __builtin_amdgcn_mfma_f32_16x16x32_f16(Ahi, Blo0, acc0, 0, 0, 0);
        acc1 = __builtin_amdgcn_mfma_f32_16x16x32_f16(Ahi, Blo1, acc1, 0, 0, 0);
        acc0 = __builtin_amdgcn_mfma_f32_16x16x32_f16(Alo, Bhi0, acc0, 0, 0, 0);
        acc1 = __builtin_amdgcn_mfma_f32_16x16x32_f16(Alo, Bhi1, acc1, 0, 0, 0);
    }

    // D layout: row = quad*4 + r (within 16-row tile), col = l15 (+16 for acc1)
#pragma unroll
    for (int r = 0; r < 4; r++) {
        size_t rr = (size_t)b * N_ + (n0 + w * 16 + quad * 4 + r);
        aout[rr * H_ + l15]      = acc0[r];
        aout[rr * H_ + 16 + l15] = acc1[r];
    }
}

// ---------------------------------------------------------------- GRU gates
__global__ __launch_bounds__(256) void k_gate(const float* __restrict__ a_in,
                                              const float* __restrict__ a_out,
                                              float* __restrict__ hstate,
                                              const float* __restrict__ Wz,
                                              const float* __restrict__ bz,
                                              const float* __restrict__ Wr,
                                              const float* __restrict__ br,
                                              const float* __restrict__ Wt,
                                              const float* __restrict__ bt) {
    __shared__ float cat[8][96];
    __shared__ float rh[8][32];
    int base = blockIdx.x * 8;     // flattened row b*512+n
    int t = threadIdx.x;

    for (int idx = t; idx < 768; idx += 256) {
        int r = idx / 96, c = idx - r * 96;
        size_t row = (size_t)(base + r);
        float v;
        if (c < 32)      v = a_in [row * 32 + c];
        else if (c < 64) v = a_out[row * 32 + (c - 32)];
        else             v = hstate[row * 32 + (c - 64)];
        cat[r][c] = v;
    }
    __syncthreads();

    int r = t >> 5, i = t & 31;
    float az = bz[i], ar = br[i];
    const f32x4* wzr = (const f32x4*)(Wz + (size_t)i * 96);
    const f32x4* wrr = (const f32x4*)(Wr + (size_t)i * 96);
    const f32x4* crow = (const f32x4*)cat[r];
#pragma unroll
    for (int kc = 0; kc < 24; kc++) {
        f32x4 cv = crow[kc];
        f32x4 wz = wzr[kc];
        f32x4 wr = wrr[kc];
        az += cv[0]*wz[0] + cv[1]*wz[1] + cv[2]*wz[2] + cv[3]*wz[3];
        ar += cv[0]*wr[0] + cv[1]*wr[1] + cv[2]*wr[2] + cv[3]*wr[3];
    }
    float z  = 1.f / (1.f + __expf(-az));
    float rg = 1.f / (1.f + __expf(-ar));
    float hold = cat[r][64 + i];
    rh[r][i] = rg * hold;
    __syncthreads();

    float at = bt[i];
    const f32x4* wtr = (const f32x4*)(Wt + (size_t)i * 96);
#pragma unroll
    for (int kc = 0; kc < 16; kc++) {     // a_in | a_out part
        f32x4 cv = crow[kc];
        f32x4 wt = wtr[kc];
        at += cv[0]*wt[0] + cv[1]*wt[1] + cv[2]*wt[2] + cv[3]*wt[3];
    }
    const f32x4* rrow = (const f32x4*)rh[r];
#pragma unroll
    for (int kc = 0; kc < 8; kc++) {      // r*h part
        f32x4 cv = rrow[kc];
        f32x4 wt = wtr[16 + kc];
        at += cv[0]*wt[0] + cv[1]*wt[1] + cv[2]*wt[2] + cv[3]*wt[3];
    }
    float hh = tanhf(at);
    hstate[(size_t)(base + r) * 32 + i] = (1.f - z) * hold + z * hh;
}

// ---------------------------------------------------------------- readout
__global__ __launch_bounds__(256) void k_final(const float* __restrict__ hstate,
                                               const float* __restrict__ a,
                                               const float* __restrict__ W1,
                                               const float* __restrict__ b1,
                                               const float* __restrict__ W2,
                                               const float* __restrict__ b2,
                                               float* __restrict__ out) {
    __shared__ float hl[8][32];
    __shared__ float as[8];
    int base = blockIdx.x * 8;
    int t = threadIdx.x;
    {
        int r = t >> 5, c = t & 31;
        hl[r][c] = hstate[(size_t)(base + r) * 32 + c];
        if (t < 8) as[t] = a[base + t];
    }
    __syncthreads();
    int r = t >> 5, j = t & 31;
    float acc = b1[j];
    const float* w1r = W1 + (size_t)j * 33;
#pragma unroll
    for (int i2 = 0; i2 < 32; i2++) acc += hl[r][i2] * w1r[i2];
    acc += as[r] * w1r[32];
    float o = tanhf(acc) * W2[j];
#pragma unroll
    for (int off = 16; off; off >>= 1) o += __shfl_xor(o, off, 32);
    if (j == 0) out[base + r] = o + b2[0];
}

// ---------------------------------------------------------------- launcher
extern "C" void kernel_launch(void* const* d_in, const int* in_sizes, int n_in,
                              void* d_out, int out_size, void* d_ws, size_t ws_size,
                              hipStream_t stream) {
    const float* x     = (const float*)d_in[0];
    const float* a     = (const float*)d_in[1];
    const float* m     = (const float*)d_in[2];
    const float* W_in  = (const float*)d_in[3];
    const float* b_in  = (const float*)d_in[4];
    const float* W_out = (const float*)d_in[5];
    const float* b_out = (const float*)d_in[6];
    const float* Wz    = (const float*)d_in[7];
    const float* bz    = (const float*)d_in[8];
    const float* Wr    = (const float*)d_in[9];
    const float* br    = (const float*)d_in[10];
    const float* Wt    = (const float*)d_in[11];
    const float* bt    = (const float*)d_in[12];
    const float* W1    = (const float*)d_in[13];
    const float* b1    = (const float*)d_in[14];
    const float* W2    = (const float*)d_in[15];
    const float* b2    = (const float*)d_in[16];
    float* out = (float*)d_out;

    char* ws = (char*)d_ws;
    float*    h         = (float*)(ws);                           // 4 MB
    float*    a_in      = (float*)(ws + ((size_t)4  << 20));      // 4 MB
    float*    a_out     = (float*)(ws + ((size_t)8  << 20));      // 4 MB
    _Float16* sT_in_hi  = (_Float16*)(ws + ((size_t)12 << 20));   // 8 MB
    _Float16* sT_in_lo  = (_Float16*)(ws + ((size_t)20 << 20));   // 8 MB
    _Float16* sT_out_hi = (_Float16*)(ws + ((size_t)28 << 20));   // 8 MB
    _Float16* sT_out_lo = (_Float16*)(ws + ((size_t)36 << 20));   // 8 MB (44 MB total)

    k_init_h<<<1024, 256, 0, stream>>>(x, h);
    for (int s = 0; s < NSTEPS; s++) {
        k_s<<<512, 256, 0, stream>>>(h, W_in, b_in, W_out, b_out,
                                     sT_in_hi, sT_in_lo, sT_out_hi, sT_out_lo);
        k_einsum<<<dim3(8, 64, 2), 256, 0, stream>>>(m, sT_in_hi, sT_in_lo,
                                                     sT_out_hi, sT_out_lo,
                                                     a_in, a_out);
        k_gate<<<4096, 256, 0, stream>>>(a_in, a_out, h, Wz, bz, Wr, br, Wt, bt);
    }
    k_final<<<4096, 256, 0, stream>>>(h, a, W1, b1, W2, b2, out);
}